// Round 4
// baseline (853.347 us; speedup 1.0000x reference)
//
#include <hip/hip_runtime.h>
#include <math.h>

#define B 64
#define P 24564
#define NC 81
#define T 24

static constexpr size_t BP = (size_t)B * P;  // 1,572,096  (== 6141 * 256 exactly)
// workspace layout (bytes)
static constexpr size_t OFF_CLOSS  = 0;                              // float[BP]
static constexpr size_t OFF_BPK    = 4 * BP;                         // u64[B*T]
static constexpr size_t OFF_NUMPOS = OFF_BPK + 8 * (size_t)(B * T);  // int[64]
static constexpr size_t OFF_ACC    = OFF_NUMPOS + 256;               // double[3]
static constexpr size_t OFF_LBL    = OFF_ACC + 256;                  // u8[BP]

__device__ inline float sl1(float d) {
    float ad = fabsf(d);
    return (ad < 1.0f) ? 0.5f * d * d : ad - 0.5f;
}

// wave64 max via DPP (VALU pipe; zero DS-pipe traffic). After the chain,
// lane 63 holds the wave max; readlane broadcasts it via SGPR.
template <int CTRL>
__device__ inline float fmax_dpp(float x) {
    int xi = __float_as_int(x);
    int yi = __builtin_amdgcn_update_dpp(xi, xi, CTRL, 0xF, 0xF, false);
    return fmaxf(x, __int_as_float(yi));
}
__device__ inline float wave_max_bcast(float x) {
    x = fmax_dpp<0x111>(x);  // row_shr:1
    x = fmax_dpp<0x112>(x);  // row_shr:2
    x = fmax_dpp<0x114>(x);  // row_shr:4
    x = fmax_dpp<0x118>(x);  // row_shr:8  -> lane15/31/47/63 = row max
    x = fmax_dpp<0x142>(x);  // row_bcast15
    x = fmax_dpp<0x143>(x);  // row_bcast31 -> lane63 = wave max
    return __int_as_float(__builtin_amdgcn_readlane(__float_as_int(x), 63));
}

// K0: init bpk keys + zero numPos/acc
__global__ void k_init(unsigned long long* __restrict__ bpk,
                       int* __restrict__ numPos, double* __restrict__ acc) {
    int i = blockIdx.x * 256 + threadIdx.x;
    if (i < B * T) bpk[i] = 0xFFFFFFFFull;  // iou=0, prior 0
    if (i < B) numPos[i] = 0;
    if (i < 3) acc[i] = 0.0;
}

// K1: match only — IOU, per-thread best-truth, per-truth best-prior (DPP max,
// one tail atomic), loc loss for pos, lbl byte per prior. No conf access.
__global__ __launch_bounds__(256) void k_match(
        const float* __restrict__ loc, const float* __restrict__ targets,
        const float* __restrict__ anchors,
        unsigned long long* __restrict__ bpk, unsigned char* __restrict__ lblArr,
        int* __restrict__ numPos, double* __restrict__ acc) {
    __shared__ float tg[T * 5];
    __shared__ double sdl[4];
    __shared__ int spc[4];

    int b = blockIdx.y;
    int tid = threadIdx.x, lane = tid & 63, w = tid >> 6;
    int p = blockIdx.x * 256 + tid;
    size_t rowBase = (size_t)b * P;

    if (tid < T * 5) tg[tid] = targets[(size_t)b * T * 5 + tid];
    __syncthreads();

    bool valid = p < P;
    int lbl = 0;
    float locC = 0.0f;
    float4 a = make_float4(0.0f, 0.0f, 1.0f, 1.0f);
    float ax1 = 0, ay1 = 0, ax2 = 0, ay2 = 0, aarea = 0;
    if (valid) {
        a = ((const float4*)anchors)[p];
        ax1 = a.x - a.z * 0.5f; ay1 = a.y - a.w * 0.5f;
        ax2 = a.x + a.z * 0.5f; ay2 = a.y + a.w * 0.5f;
        aarea = (ax2 - ax1) * (ay2 - ay1);
    }
    int waveP0 = blockIdx.x * 256 + (tid & ~63);
    float bestOv = -1.0f; int bestT = 0;
    unsigned long long myKey = 0;   // lane t holds winner key for truth t
    #pragma unroll 4
    for (int t = 0; t < T; ++t) {
        float tx1 = tg[t * 5 + 0], ty1 = tg[t * 5 + 1];
        float tx2 = tg[t * 5 + 2], ty2 = tg[t * 5 + 3];
        float iou = 0.0f;
        if (valid) {
            float lx = fmaxf(tx1, ax1), ly = fmaxf(ty1, ay1);
            float rx = fminf(tx2, ax2), ry = fminf(ty2, ay2);
            float ww = fmaxf(rx - lx, 0.0f), hh = fmaxf(ry - ly, 0.0f);
            float inter = ww * hh;
            float ta = (tx2 - tx1) * (ty2 - ty1);
            iou = inter / (ta + aarea - inter);
        }
        if (iou > bestOv) { bestOv = iou; bestT = t; }  // first-occurrence argmax
        float mx = wave_max_bcast(iou);                  // VALU-only reduce
        unsigned long long bal = __ballot(iou == mx);
        int src = __ffsll(bal) - 1;                      // lowest lane = lowest p
        unsigned int bp = (unsigned)(waveP0 + src);
        unsigned long long key = ((unsigned long long)__float_as_uint(mx) << 32)
                               | (unsigned long long)(0xFFFFFFFFu - bp);
        if (lane == t) myKey = key;                      // cndmask, no branch
    }
    if (lane < T) atomicMax(&bpk[b * T + lane], myKey);  // one vector atomic
    if (valid && bestOv > 0.5f) {
        int tIdx = bestT;
        float x1 = tg[tIdx * 5 + 0], y1 = tg[tIdx * 5 + 1];
        float x2 = tg[tIdx * 5 + 2], y2 = tg[tIdx * 5 + 3];
        lbl = (int)tg[tIdx * 5 + 4];  // >= 1
        float cx = (x1 + x2) * 0.5f, cy = (y1 + y2) * 0.5f;
        float ww = x2 - x1, hh = y2 - y1;
        float e0 = (cx - a.x) / a.z;
        float e1 = (cy - a.y) / a.w;
        float e2 = logf(ww) - logf(a.z);
        float e3 = logf(hh) - logf(a.w);
        float4 lp = ((const float4*)loc)[rowBase + p];
        locC = sl1(lp.x - e0) + sl1(lp.y - e1) + sl1(lp.z - e2) + sl1(lp.w - e3);
    }
    if (valid) lblArr[rowBase + p] = (unsigned char)lbl;

    // ---- block reduction -> global atomics (loc, numPos) ----
    double dl = (double)locC;
    int pc = (lbl > 0) ? 1 : 0;
    #pragma unroll
    for (int off = 32; off > 0; off >>= 1) {
        dl += __shfl_down(dl, off, 64);
        pc += __shfl_down(pc, off, 64);
    }
    if (lane == 0) { sdl[w] = dl; spc[w] = pc; }
    __syncthreads();
    if (tid == 0) {
        atomicAdd(&acc[0], sdl[0] + sdl[1] + sdl[2] + sdl[3]);
        atomicAdd(&numPos[b], spc[0] + spc[1] + spc[2] + spc[3]);
    }
}

// K2: conf lse scan — one thread per row, LDS-free, DS-free, barrier-free.
// Aligned float4 window: row*81 floats shifted left by c = row&3 floats is
// 16B-aligned; quad 0 masks e>=c, quad 20 masks e<=c; never reads OOB
// (row 0 has c=0, last row BP-1 has c=3).
__global__ __launch_bounds__(256) void k_conf(
        const float* __restrict__ conf, const unsigned char* __restrict__ lblArr,
        float* __restrict__ closs, double* __restrict__ acc) {
    __shared__ double sdc[4];
    int tid = threadIdx.x, lane = tid & 63, w = tid >> 6;
    int gid = blockIdx.x * 256 + tid;          // 0..BP-1, grid exact
    int c = gid & 3;
    const float* base = conf + ((size_t)gid * (size_t)NC - (size_t)c);
    const float4* q4 = (const float4*)base;

    float4 v = q4[0];
    float s0 = (c <= 0) ? __expf(v.x) : 0.0f;
    float s1 = (c <= 1) ? __expf(v.y) : 0.0f;
    float s2 = (c <= 2) ? __expf(v.z) : 0.0f;
    float s3 = __expf(v.w);                    // e=3 always valid
    float x0 = (c == 0) ? v.x : ((c == 1) ? v.y : ((c == 2) ? v.z : v.w));
    #pragma unroll
    for (int k = 1; k < 20; ++k) {
        float4 u = q4[k];
        s0 += __expf(u.x); s1 += __expf(u.y);
        s2 += __expf(u.z); s3 += __expf(u.w);
    }
    float4 t = q4[20];
    s0 += __expf(t.x);                         // e=0 always valid
    s1 += (c >= 1) ? __expf(t.y) : 0.0f;
    s2 += (c >= 2) ? __expf(t.z) : 0.0f;
    s3 += (c >= 3) ? __expf(t.w) : 0.0f;
    float lse = __logf((s0 + s1) + (s2 + s3));

    int lbl = lblArr[gid];
    double dc = 0.0;
    float cl;
    if (lbl > 0) {
        float xs = base[c + lbl];              // conf[gid*81 + lbl]
        dc = (double)(lse - xs);
        cl = 0.0f;
    } else {
        cl = fmaxf(lse - x0, 0.0f);
    }
    closs[gid] = cl;

    #pragma unroll
    for (int off = 32; off > 0; off >>= 1) dc += __shfl_down(dc, off, 64);
    if (lane == 0) sdc[w] = dc;
    __syncthreads();
    if (tid == 0) atomicAdd(&acc[1], sdc[0] + sdc[1] + sdc[2] + sdc[3]);
}

// K_fix: repair ph-branch priors (best-prior of truths with best_truth_overlap
// <= 0.5). <= B*T priors. IOU expression order matches k_match bitwise.
__global__ __launch_bounds__(128) void k_fix(
        const float* __restrict__ loc, const float* __restrict__ conf,
        const float* __restrict__ targets, const float* __restrict__ anchors,
        const unsigned long long* __restrict__ bpk,
        float* __restrict__ closs, int* __restrict__ numPos, double* __restrict__ acc) {
    int b = blockIdx.x;
    int tid = threadIdx.x;
    __shared__ float tg[T * 5];
    __shared__ unsigned int bpS[T];
    if (tid < T * 5) tg[tid] = targets[(size_t)b * T * 5 + tid];
    if (tid >= 96 && tid < 96 + T)
        bpS[tid - 96] = 0xFFFFFFFFu - (unsigned)(bpk[b * T + tid - 96] & 0xFFFFFFFFull);
    __syncthreads();
    double dLoc = 0.0, dCls = 0.0;
    int dPos = 0;
    if (tid < T) {
        int t = tid;
        unsigned int pp = bpS[t];
        bool owner = true;                        // last t with this prior wins
        for (int t2 = t + 1; t2 < T; ++t2) if (bpS[t2] == pp) owner = false;
        if (owner) {
            float4 a = ((const float4*)anchors)[pp];
            float ax1 = a.x - a.z * 0.5f, ay1 = a.y - a.w * 0.5f;
            float ax2 = a.x + a.z * 0.5f, ay2 = a.y + a.w * 0.5f;
            float aarea = (ax2 - ax1) * (ay2 - ay1);
            float bestOv = -1.0f;
            for (int t2 = 0; t2 < T; ++t2) {
                float tx1 = tg[t2 * 5 + 0], ty1 = tg[t2 * 5 + 1];
                float tx2 = tg[t2 * 5 + 2], ty2 = tg[t2 * 5 + 3];
                float lx = fmaxf(tx1, ax1), ly = fmaxf(ty1, ay1);
                float rx = fminf(tx2, ax2), ry = fminf(ty2, ay2);
                float ww = fmaxf(rx - lx, 0.0f), hh = fmaxf(ry - ly, 0.0f);
                float inter = ww * hh;
                float ta = (tx2 - tx1) * (ty2 - ty1);
                float iou = inter / (ta + aarea - inter);
                if (iou > bestOv) bestOv = iou;
            }
            if (!(bestOv > 0.5f)) {
                float x1 = tg[t * 5 + 0], y1 = tg[t * 5 + 1];
                float x2 = tg[t * 5 + 2], y2 = tg[t * 5 + 3];
                int lbl = (int)tg[t * 5 + 4];     // >= 1
                float cx = (x1 + x2) * 0.5f, cy = (y1 + y2) * 0.5f;
                float ww = x2 - x1, hh = y2 - y1;
                float e0 = (cx - a.x) / a.z;
                float e1 = (cy - a.y) / a.w;
                float e2 = logf(ww) - logf(a.z);
                float e3 = logf(hh) - logf(a.w);
                float4 lp = ((const float4*)loc)[(size_t)b * P + pp];
                float locC = sl1(lp.x - e0) + sl1(lp.y - e1) + sl1(lp.z - e2) + sl1(lp.w - e3);
                dLoc = (double)locC;
                dPos = 1;
                const float* cc = conf + ((size_t)b * P + pp) * (size_t)NC;
                float s0 = 0.0f, s1 = 0.0f, s2 = 0.0f, s3 = 0.0f;
                #pragma unroll
                for (int k = 0; k < 20; ++k) {
                    s0 += __expf(cc[4 * k + 0]);
                    s1 += __expf(cc[4 * k + 1]);
                    s2 += __expf(cc[4 * k + 2]);
                    s3 += __expf(cc[4 * k + 3]);
                }
                s0 += __expf(cc[80]);
                float lse = __logf((s0 + s1) + (s2 + s3));
                float xs = cc[lbl];
                dCls = (double)(lse - xs);
                closs[(size_t)b * P + pp] = 0.0f;  // pos prior -> closs 0
            }
        }
    }
    #pragma unroll
    for (int off = 32; off > 0; off >>= 1) {
        dLoc += __shfl_down(dLoc, off, 64);
        dCls += __shfl_down(dCls, off, 64);
        dPos += __shfl_down(dPos, off, 64);
    }
    if (tid == 0) {
        if (dLoc != 0.0) atomicAdd(&acc[0], dLoc);
        if (dCls != 0.0) atomicAdd(&acc[1], dCls);
        if (dPos) atomicAdd(&numPos[b], dPos);
    }
}

// K3: per-batch radix-select K-th largest closs, top-K sum (tie-invariant).
// Histogram updates use ballot-aggregation: closs values cluster in very few
// digit bins, so per-element LDS atomics serialize ~24K deep; one atomic per
// (wave x distinct digit) instead.
__global__ __launch_bounds__(1024) void k_select(
        const float* __restrict__ closs, const int* __restrict__ numPos,
        double* __restrict__ acc) {
    int b = blockIdx.x;
    int tid = threadIdx.x;
    int np = numPos[b];
    long long Kl = 3LL * np;
    int K = (int)(Kl < (long long)(P - 1) ? Kl : (long long)(P - 1));
    if (K <= 0) return;
    const float* row = closs + (size_t)b * P;
    __shared__ unsigned int hist[256];
    __shared__ unsigned int s_prefix;
    __shared__ int s_rem;
    __shared__ double sred[16];
    __shared__ int cred[16];
    if (tid == 0) { s_prefix = 0; s_rem = K; }
    __syncthreads();
    for (int rd = 3; rd >= 0; --rd) {
        if (tid < 256) hist[tid] = 0;
        __syncthreads();
        unsigned int prefix = s_prefix;
        int rem = s_rem;
        for (int i = tid; i < P; i += 1024) {
            unsigned int bits = __float_as_uint(row[i]);
            bool take = (rd == 3) || ((bits >> ((rd + 1) * 8)) == prefix);
            if (take) {
                unsigned int d = (bits >> (rd * 8)) & 0xFFu;
                unsigned long long m = __ballot(true);   // active (taking) lanes
                #pragma unroll
                for (int bit = 0; bit < 8; ++bit) {
                    unsigned long long bb = __ballot(((d >> bit) & 1u) != 0u);
                    m &= ((d >> bit) & 1u) ? bb : ~bb;
                }
                int leader = __ffsll(m) - 1;
                if ((tid & 63) == leader)
                    atomicAdd(&hist[d], (unsigned)__popcll(m));
            }
        }
        __syncthreads();
        if (tid < 64) {
            unsigned int h0 = hist[4 * tid + 0], h1 = hist[4 * tid + 1];
            unsigned int h2 = hist[4 * tid + 2], h3 = hist[4 * tid + 3];
            unsigned int S = h0 + h1 + h2 + h3;
            #pragma unroll
            for (int off = 1; off < 64; off <<= 1) {   // inclusive suffix scan
                unsigned int up = __shfl_down(S, off, 64);
                if (tid + off < 64) S += up;
            }
            unsigned int above = __shfl_down(S, 1, 64);
            if (tid == 63) above = 0;
            if ((unsigned)rem <= S && (unsigned)rem > above) {
                int rr = rem - (int)above;
                int digit;
                if (rr <= (int)h3) digit = 4 * tid + 3;
                else { rr -= h3;
                    if (rr <= (int)h2) digit = 4 * tid + 2;
                    else { rr -= h2;
                        if (rr <= (int)h1) digit = 4 * tid + 1;
                        else { rr -= h1; digit = 4 * tid; } } }
                s_prefix = (prefix << 8) | (unsigned)digit;
                s_rem = rr;
            }
        }
        __syncthreads();
    }
    unsigned int tbits = s_prefix;
    float tval = __uint_as_float(tbits);
    int cg = 0;
    double sg = 0.0;
    for (int i = tid; i < P; i += 1024) {
        float v = row[i];
        if (__float_as_uint(v) > tbits) { cg++; sg += (double)v; }
    }
    int lane = tid & 63, w = tid >> 6;
    #pragma unroll
    for (int off = 32; off > 0; off >>= 1) {
        sg += __shfl_down(sg, off, 64);
        cg += __shfl_down(cg, off, 64);
    }
    if (lane == 0) { sred[w] = sg; cred[w] = cg; }
    __syncthreads();
    if (tid == 0) {
        double sgT = 0.0; int cgT = 0;
        #pragma unroll
        for (int i = 0; i < 16; ++i) { sgT += sred[i]; cgT += cred[i]; }
        atomicAdd(&acc[2], sgT + (double)(K - cgT) * (double)tval);
    }
}

// K4: finalize
__global__ void k_final(const int* __restrict__ numPos, const double* __restrict__ acc,
                        float* __restrict__ out) {
    int lane = threadIdx.x;  // 64 threads, B=64
    int np = numPos[lane];
    long long Kl = 3LL * np;
    long long K = Kl < (long long)(P - 1) ? Kl : (long long)(P - 1);
    long long sel = (long long)np + K;  // pos/neg disjoint
    int N = np;
    #pragma unroll
    for (int off = 32; off > 0; off >>= 1) {
        N += __shfl_down(N, off, 64);
        sel += __shfl_down(sel, off, 64);
    }
    if (lane == 0) {
        double n = (double)N;
        double nonsel = (double)((long long)B * (long long)P - sel);
        double cls = acc[1] + acc[2] + nonsel * 4.3944491546724391;  // ln(81)
        out[0] = (float)(acc[0] / n);
        out[1] = (float)(cls / n);
    }
}

extern "C" void kernel_launch(void* const* d_in, const int* in_sizes, int n_in,
                              void* d_out, int out_size, void* d_ws, size_t ws_size,
                              hipStream_t stream) {
    const float* loc     = (const float*)d_in[0];
    const float* conf    = (const float*)d_in[1];
    const float* targets = (const float*)d_in[2];
    const float* anchors = (const float*)d_in[3];
    float* out = (float*)d_out;
    char* ws = (char*)d_ws;

    float* closs  = (float*)(ws + OFF_CLOSS);
    unsigned long long* bpk = (unsigned long long*)(ws + OFF_BPK);
    int* numPos   = (int*)(ws + OFF_NUMPOS);
    double* acc   = (double*)(ws + OFF_ACC);
    unsigned char* lblArr = (unsigned char*)(ws + OFF_LBL);

    k_init<<<6, 256, 0, stream>>>(bpk, numPos, acc);
    dim3 g1((P + 255) / 256, B);
    k_match<<<g1, 256, 0, stream>>>(loc, targets, anchors, bpk, lblArr,
                                    numPos, acc);
    k_conf<<<(int)(BP / 256), 256, 0, stream>>>(conf, lblArr, closs, acc);
    k_fix<<<B, 128, 0, stream>>>(loc, conf, targets, anchors, bpk,
                                 closs, numPos, acc);
    k_select<<<B, 1024, 0, stream>>>(closs, numPos, acc);
    k_final<<<1, 64, 0, stream>>>(numPos, acc, out);
}